// Round 3
// baseline (415.349 us; speedup 1.0000x reference)
//
#include <hip/hip_runtime.h>
#include <hip/hip_bf16.h>

// TriangleMultiplication on MI355X (gfx950).
// Pipeline: k_prep (weights->bf16,T) ; k_proj<0> (leftT) ; k_proj<1> (rightTT) ;
//           k_tri (128x batched 512^3 bf16 MFMA GEMM) ; k_final (Wo + gate + residual + LN).
// ws layout: WlT|WrT|WgT|WoT (4*32KB) + leftT (64MB) + rightTT (64MB) + tri (64MB) = ~192.2MB

#define LSZ 512
#define NPOS (LSZ * LSZ)  // 262144 positions

typedef short s16;
typedef __attribute__((ext_vector_type(4))) short s16x4;
typedef __attribute__((ext_vector_type(8))) short s16x8;
typedef __attribute__((ext_vector_type(4))) float f32x4;

typedef const __attribute__((address_space(1))) unsigned int* gas1;
typedef __attribute__((address_space(3))) unsigned int* las3;

static __device__ __forceinline__ s16 f2bf(float f) {
    // round-to-nearest-even fp32 -> bf16 (finite values)
    unsigned int u = __builtin_bit_cast(unsigned int, f);
    u += 0x7FFFu + ((u >> 16) & 1u);
    return (s16)(u >> 16);
}

static __device__ __forceinline__ void gload_lds16(const void* g, void* l) {
    // 16B-per-lane async global->LDS; LDS dest must be wave-uniform base (+lane*16 in HW)
    __builtin_amdgcn_global_load_lds((gas1)g, (las3)l, 16, 0, 0);
}

// ---------------- K0: transpose weights to bf16 [out][in] ----------------
__global__ void k_prep(const float* __restrict__ Wl, const float* __restrict__ Wr,
                       const float* __restrict__ Wg, const float* __restrict__ Wo,
                       s16* __restrict__ WlT, s16* __restrict__ WrT,
                       s16* __restrict__ WgT, s16* __restrict__ WoT) {
    const float* src;
    s16* dst;
    switch (blockIdx.x) {
        case 0: src = Wl; dst = WlT; break;
        case 1: src = Wr; dst = WrT; break;
        case 2: src = Wg; dst = WgT; break;
        default: src = Wo; dst = WoT; break;
    }
    for (int e = threadIdx.x; e < 128 * 128; e += blockDim.x) {
        int o = e >> 7, i = e & 127;
        dst[e] = f2bf(src[i * 128 + o]);  // WT[o][i] = W[i][o]
    }
}

// ---------------- K1: projection GEMM, output transposed [h][pos] ----------------
// COLMODE=0: block b covers linear positions b*128.. (writes leftT[h][pos])
// COLMODE=1: block b covers a column strip (r=rb*128..+128, c fixed) -> rightTT[h][c][r]
template <int COLMODE>
__global__ __launch_bounds__(256) void k_proj(const float* __restrict__ pair,
                                              const s16* __restrict__ WT,
                                              const float* __restrict__ bias,
                                              s16* __restrict__ outT) {
    __shared__ __align__(16) s16 As[128 * 128];  // 32KB, XOR-swizzled rows (256B)
    const int t = threadIdx.x;
    const int b = blockIdx.x;
    const int c0 = b & 511, rb = b >> 9;  // used when COLMODE==1
    // ---- stage: 128 pos x 128 d fp32 -> bf16 LDS ----
    {
        const int p = t >> 1;
        const int dh = (t & 1) << 6;  // 0 or 64
        long gpos = COLMODE ? ((long)(rb * 128 + p) * 512 + c0) : ((long)b * 128 + p);
        const float* src = pair + gpos * 128 + dh;
        const int swz = (p & 7) << 4;
        char* lrow = (char*)As + p * 256;
#pragma unroll
        for (int g = 0; g < 8; ++g) {
            f32x4 v0 = *(const f32x4*)(src + g * 8);
            f32x4 v1 = *(const f32x4*)(src + g * 8 + 4);
            s16x8 pk;
            pk[0] = f2bf(v0[0]); pk[1] = f2bf(v0[1]); pk[2] = f2bf(v0[2]); pk[3] = f2bf(v0[3]);
            pk[4] = f2bf(v1[0]); pk[5] = f2bf(v1[1]); pk[6] = f2bf(v1[2]); pk[7] = f2bf(v1[3]);
            *(s16x8*)(lrow + ((dh * 2 + g * 16) ^ swz)) = pk;
        }
    }
    __syncthreads();
    // ---- 4 waves, each 64 pos x 64 h, K=128 ----
    const int w = t >> 6, l = t & 63;
    const int wr = (w >> 1) * 64, wc = (w & 1) * 64;
    const int lr = l & 15, lg = l >> 4;
    f32x4 acc[4][4];
#pragma unroll
    for (int mi = 0; mi < 4; ++mi)
#pragma unroll
        for (int ni = 0; ni < 4; ++ni) acc[mi][ni] = (f32x4){0.f, 0.f, 0.f, 0.f};
#pragma unroll
    for (int ks = 0; ks < 4; ++ks) {
        const int kk = ks * 32 + lg * 8;
        s16x8 af[4], bfv[4];
#pragma unroll
        for (int mi = 0; mi < 4; ++mi) {
            int row = wr + mi * 16 + lr;
            af[mi] = *(const s16x8*)((const char*)As + ((row * 256 + kk * 2) ^ ((row & 7) << 4)));
        }
#pragma unroll
        for (int ni = 0; ni < 4; ++ni) {
            int h = wc + ni * 16 + lr;
            bfv[ni] = *(const s16x8*)(WT + h * 128 + kk);  // WT is [h][d], L1-resident
        }
#pragma unroll
        for (int mi = 0; mi < 4; ++mi)
#pragma unroll
            for (int ni = 0; ni < 4; ++ni)
                acc[mi][ni] = __builtin_amdgcn_mfma_f32_16x16x32_bf16(af[mi], bfv[ni], acc[mi][ni], 0, 0, 0);
    }
    // ---- epilogue: +bias, bf16, store [h][pos] (4 consecutive pos -> 8B store) ----
#pragma unroll
    for (int ni = 0; ni < 4; ++ni) {
        const int h = wc + ni * 16 + lr;
        const float bv = bias[h];
        long base = (long)h * NPOS + (COLMODE ? ((long)c0 * 512 + rb * 128) : ((long)b * 128));
#pragma unroll
        for (int mi = 0; mi < 4; ++mi) {
            const int prow = wr + mi * 16 + lg * 4;
            s16x4 pk;
#pragma unroll
            for (int r = 0; r < 4; ++r) pk[r] = f2bf(acc[mi][ni][r] + bv);
            *(s16x4*)(outT + base + prow) = pk;
        }
    }
}

// ---------------- K2: triangle einsum = 128 batched 512^3 GEMMs ----------------
// C_h[i][j] = sum_k leftT[h][i][k] * rightTT[h][j][k]   (A row-major, B in B^T form)
__global__ __launch_bounds__(256) void k_tri(const s16* __restrict__ leftT,
                                             const s16* __restrict__ rightTT,
                                             s16* __restrict__ tri) {
    __shared__ __align__(16) s16 As[128 * 64];  // 16KB each, XOR-swizzled
    __shared__ __align__(16) s16 Bs[128 * 64];
    const int t = threadIdx.x;
    // XCD swizzle: all 16 tiles of one h-GEMM land on one XCD (2048 % 8 == 0, bijective)
    const int logical = ((blockIdx.x & 7) << 8) | (blockIdx.x >> 3);
    const int h = logical >> 4;
    const int ti = (logical >> 2) & 3, tj = logical & 3;
    const s16* Ap = leftT + (long)h * NPOS + ti * 128 * 512;
    const s16* Bp = rightTT + (long)h * NPOS + tj * 128 * 512;
    const int w = t >> 6, l = t & 63;
    const int wr = (w >> 1) * 64, wc = (w & 1) * 64;
    const int lr = l & 15, lg = l >> 4;
    const int srow = t >> 3;       // staging row within 32-row chunk
    const int skk = (t & 7) << 3;  // staging k offset (8 elems)
    f32x4 acc[4][4];
#pragma unroll
    for (int mi = 0; mi < 4; ++mi)
#pragma unroll
        for (int ni = 0; ni < 4; ++ni) acc[mi][ni] = (f32x4){0.f, 0.f, 0.f, 0.f};
    for (int kb = 0; kb < 512; kb += 64) {
        __syncthreads();  // LDS reuse guard
        // stage A,B tiles (128x64 bf16 each) via global_load_lds, source pre-swizzled
#pragma unroll
        for (int P = 0; P < 4; ++P) {
            int row = P * 32 + srow;
            int kks = skk ^ ((row & 7) << 3);  // inverse of read-side XOR (involution)
            unsigned loff = P * 4096 + w * 1024;
            gload_lds16(Ap + row * 512 + kb + kks, (char*)As + loff);
            gload_lds16(Bp + row * 512 + kb + kks, (char*)Bs + loff);
        }
        __syncthreads();
#pragma unroll
        for (int ks = 0; ks < 2; ++ks) {
            const int kk = ks * 32 + lg * 8;
            s16x8 af[4], bfv[4];
#pragma unroll
            for (int mi = 0; mi < 4; ++mi) {
                int row = wr + mi * 16 + lr;
                af[mi] = *(const s16x8*)((const char*)As + ((row * 128 + kk * 2) ^ ((row & 7) << 4)));
            }
#pragma unroll
            for (int ni = 0; ni < 4; ++ni) {
                int row = wc + ni * 16 + lr;
                bfv[ni] = *(const s16x8*)((const char*)Bs + ((row * 128 + kk * 2) ^ ((row & 7) << 4)));
            }
#pragma unroll
            for (int mi = 0; mi < 4; ++mi)
#pragma unroll
                for (int ni = 0; ni < 4; ++ni)
                    acc[mi][ni] = __builtin_amdgcn_mfma_f32_16x16x32_bf16(af[mi], bfv[ni], acc[mi][ni], 0, 0, 0);
        }
    }
    // epilogue: bf16 store to tri[h][i][j] (lanes 0-15 contiguous j)
#pragma unroll
    for (int mi = 0; mi < 4; ++mi) {
#pragma unroll
        for (int r = 0; r < 4; ++r) {
            int i = ti * 128 + wr + mi * 16 + lg * 4 + r;
            s16* dst = tri + (long)h * NPOS + (long)i * 512 + tj * 128 + wc;
#pragma unroll
            for (int ni = 0; ni < 4; ++ni) dst[ni * 16 + lr] = f2bf(acc[mi][ni][r]);
        }
    }
}

// ---------------- K3: out2 = tri@Wo+bo ; gate = sigmoid(pair@Wg+bg) ;
//                  y = LN(pair + gate*out2)*gamma + beta ----------------
// v3: 8 waves, 128-pos tiles, 4 tiles/block with double-buffered Ts prefetch
// (counted vmcnt, raw s_barrier). Phase-split GEMMs so each 32KB weight is
// L1-resident during its MFMA phase. Ts XOR-swizzled on 16B units via
// pre-swizzled global source (rule: both-sides-or-neither).
#define FTILES 4
__global__ __launch_bounds__(512) void k_final(const float* __restrict__ pair,
                                               const s16* __restrict__ tri,
                                               const s16* __restrict__ WgT,
                                               const s16* __restrict__ WoT,
                                               const float* __restrict__ bgv,
                                               const float* __restrict__ bov,
                                               const float* __restrict__ gam,
                                               const float* __restrict__ bet,
                                               float* __restrict__ out) {
    __shared__ __align__(16) s16 Ts[2][128 * 128];  // 2 x 32KB tri tile [h][posl]
    const int t = threadIdx.x;
    const int w = t >> 6, l = t & 63;
    const int lr = l & 15, lg = l >> 4;
    const int pw = w << 4;  // wave's 16-pos slice of the 128-pos tile
    const int tile0 = blockIdx.x * FTILES;

    // stage tri tile: 2048 16B-units; unit U -> h=U>>4, lds_u=U&15; global unit
    // pre-swizzled by g(h)=(h>>3)&7 so swizzled reads see linear data (involution)
    auto stage = [&](int buf, int tile) {
        const long pb = (long)tile * 128;
#pragma unroll
        for (int P = 0; P < 4; ++P) {
            const int U = P * 512 + t;
            const int h = U >> 4, uL = U & 15;
            const int ug = uL ^ ((h >> 3) & 7);
            gload_lds16(tri + (long)h * NPOS + pb + (ug << 3),
                        (char*)Ts[buf] + (long)(P * 512 + w * 64) * 16);
        }
    };

    stage(0, tile0);
    for (int it = 0; it < FTILES; ++it) {
        const int buf = it & 1;
        if (it == 0)
            asm volatile("s_waitcnt vmcnt(0)" ::: "memory");
        else
            asm volatile("s_waitcnt vmcnt(8)" ::: "memory");  // prefetch = newest 8
        __builtin_amdgcn_s_barrier();
        if (it + 1 < FTILES) stage(buf ^ 1, tile0 + it + 1);  // overlap with compute
        const long posT = (long)(tile0 + it) * 128;

        // pair A-fragments for the gate GEMM: issue all 8 loads up front,
        // consumed in phase G (phase O hides the latency)
        f32x4 pf0[4], pf1[4];
        {
            const float* prow = pair + (posT + pw + lr) * 128;
#pragma unroll
            for (int ks = 0; ks < 4; ++ks) {
                const int kk = ks * 32 + lg * 8;
                pf0[ks] = *(const f32x4*)(prow + kk);
                pf1[ks] = *(const f32x4*)(prow + kk + 4);
            }
        }
        // ---- phase O: accO = tri_tile^T @ WoT (LDS gather + L1-resident WoT) ----
        f32x4 accO[8];
#pragma unroll
        for (int ni = 0; ni < 8; ++ni) accO[ni] = (f32x4){0.f, 0.f, 0.f, 0.f};
#pragma unroll
        for (int ks = 0; ks < 4; ++ks) {
            const int kk = ks * 32 + lg * 8;
            const int posl = pw + lr;
            s16x8 ao;
#pragma unroll
            for (int j = 0; j < 8; ++j) {
                const int h = kk + j;
                ao[j] = Ts[buf][h * 128 + ((((posl >> 3) ^ ((h >> 3) & 7))) << 3) + (posl & 7)];
            }
#pragma unroll
            for (int ni = 0; ni < 8; ++ni) {
                const int d = ni * 16 + lr;
                s16x8 b8 = *(const s16x8*)(WoT + d * 128 + kk);
                accO[ni] = __builtin_amdgcn_mfma_f32_16x16x32_bf16(ao, b8, accO[ni], 0, 0, 0);
            }
        }
        // ---- phase G: accG = pair_tile @ WgT ----
        f32x4 accG[8];
#pragma unroll
        for (int ni = 0; ni < 8; ++ni) accG[ni] = (f32x4){0.f, 0.f, 0.f, 0.f};
#pragma unroll
        for (int ks = 0; ks < 4; ++ks) {
            const int kk = ks * 32 + lg * 8;
            s16x8 ag;
            ag[0] = f2bf(pf0[ks][0]); ag[1] = f2bf(pf0[ks][1]);
            ag[2] = f2bf(pf0[ks][2]); ag[3] = f2bf(pf0[ks][3]);
            ag[4] = f2bf(pf1[ks][0]); ag[5] = f2bf(pf1[ks][1]);
            ag[6] = f2bf(pf1[ks][2]); ag[7] = f2bf(pf1[ks][3]);
#pragma unroll
            for (int ni = 0; ni < 8; ++ni) {
                const int d = ni * 16 + lr;
                s16x8 b8 = *(const s16x8*)(WgT + d * 128 + kk);
                accG[ni] = __builtin_amdgcn_mfma_f32_16x16x32_bf16(ag, b8, accG[ni], 0, 0, 0);
            }
        }
        // ---- P3: gate, residual (pair re-read is L2-hot) ----
        float xv[8][4];
#pragma unroll
        for (int ni = 0; ni < 8; ++ni) {
            const int d = ni * 16 + lr;
            const float bgs = bgv[d], bos = bov[d];
#pragma unroll
            for (int r = 0; r < 4; ++r) {
                const long pos = posT + pw + lg * 4 + r;
                const float pv = pair[pos * 128 + d];
                const float gl = accG[ni][r] + bgs;
                const float gate = 1.f / (1.f + __expf(-gl));
                xv[ni][r] = pv + gate * (accO[ni][r] + bos);
            }
        }
        // ---- P4: LayerNorm over d (16 lr-lanes x 8 frags), frag-layout stores ----
        float gmv[8], btv[8];
#pragma unroll
        for (int ni = 0; ni < 8; ++ni) {
            const int d = ni * 16 + lr;
            gmv[ni] = gam[d];
            btv[ni] = bet[d];
        }
#pragma unroll
        for (int r = 0; r < 4; ++r) {
            float s = 0.f;
#pragma unroll
            for (int ni = 0; ni < 8; ++ni) s += xv[ni][r];
            s += __shfl_xor(s, 1); s += __shfl_xor(s, 2);
            s += __shfl_xor(s, 4); s += __shfl_xor(s, 8);
            const float mu = s * 0.0078125f;
            float v = 0.f;
#pragma unroll
            for (int ni = 0; ni < 8; ++ni) { float dd = xv[ni][r] - mu; v += dd * dd; }
            v += __shfl_xor(v, 1); v += __shfl_xor(v, 2);
            v += __shfl_xor(v, 4); v += __shfl_xor(v, 8);
            const float rstd = rsqrtf(v * 0.0078125f + 1e-5f);
            const long pos = posT + pw + lg * 4 + r;
#pragma unroll
            for (int ni = 0; ni < 8; ++ni) {
                const int d = ni * 16 + lr;
                out[pos * 128 + d] = (xv[ni][r] - mu) * rstd * gmv[ni] + btv[ni];
            }
        }
    }
}

extern "C" void kernel_launch(void* const* d_in, const int* in_sizes, int n_in,
                              void* d_out, int out_size, void* d_ws, size_t ws_size,
                              hipStream_t stream) {
    const float* pair = (const float*)d_in[0];
    const float* Wl   = (const float*)d_in[1];
    const float* bl   = (const float*)d_in[2];
    const float* Wr   = (const float*)d_in[3];
    const float* br   = (const float*)d_in[4];
    const float* Wo   = (const float*)d_in[5];
    const float* bo   = (const float*)d_in[6];
    const float* Wg   = (const float*)d_in[7];
    const float* bg   = (const float*)d_in[8];
    const float* gam  = (const float*)d_in[9];
    const float* bet  = (const float*)d_in[10];
    float* out = (float*)d_out;

    s16* WlT = (s16*)d_ws;
    s16* WrT = WlT + 128 * 128;
    s16* WgT = WrT + 128 * 128;
    s16* WoT = WgT + 128 * 128;
    s16* leftT   = WoT + 128 * 128;            // [128][NPOS]
    s16* rightTT = leftT + (long)128 * NPOS;   // [128][NPOS] (j-major, k fast)
    s16* tri     = rightTT + (long)128 * NPOS; // [128][NPOS]

    k_prep<<<4, 256, 0, stream>>>(Wl, Wr, Wg, Wo, WlT, WrT, WgT, WoT);
    k_proj<0><<<2048, 256, 0, stream>>>(pair, WlT, bl, leftT);
    k_proj<1><<<2048, 256, 0, stream>>>(pair, WrT, br, rightTT);
    k_tri<<<2048, 256, 0, stream>>>(leftT, rightTT, tri);
    k_final<<<512, 512, 0, stream>>>(pair, tri, WgT, WoT, bg, bo, gam, bet, out);
}

// Round 5
// 374.337 us; speedup vs baseline: 1.1096x; 1.1096x over previous
//
#include <hip/hip_runtime.h>
#include <hip/hip_bf16.h>

// TriangleMultiplication on MI355X (gfx950).
// Pipeline: k_prep ; k_proj<0> (leftT) ; k_proj<1> (rightTT) ; k_tri (tri[h][pos]) ;
//           k_trT (tri -> triT[pos][h], reuses leftT space) ; k_final (streaming, no LDS).
// ws layout: WlT|WrT|WgT|WoT (4*32KB) + leftT/triT (64MB) + rightTT (64MB) + tri (64MB)

#define LSZ 512
#define NPOS (LSZ * LSZ)  // 262144 positions

typedef short s16;
typedef __attribute__((ext_vector_type(4))) short s16x4;
typedef __attribute__((ext_vector_type(8))) short s16x8;
typedef __attribute__((ext_vector_type(4))) float f32x4;

typedef const __attribute__((address_space(1))) unsigned int* gas1;
typedef __attribute__((address_space(3))) unsigned int* las3;

static __device__ __forceinline__ s16 f2bf(float f) {
    unsigned int u = __builtin_bit_cast(unsigned int, f);
    u += 0x7FFFu + ((u >> 16) & 1u);
    return (s16)(u >> 16);
}

static __device__ __forceinline__ void gload_lds16(const void* g, void* l) {
    __builtin_amdgcn_global_load_lds((gas1)g, (las3)l, 16, 0, 0);
}

// ---------------- K0: transpose weights to bf16 [out][in] ----------------
__global__ void k_prep(const float* __restrict__ Wl, const float* __restrict__ Wr,
                       const float* __restrict__ Wg, const float* __restrict__ Wo,
                       s16* __restrict__ WlT, s16* __restrict__ WrT,
                       s16* __restrict__ WgT, s16* __restrict__ WoT) {
    const float* src;
    s16* dst;
    switch (blockIdx.x) {
        case 0: src = Wl; dst = WlT; break;
        case 1: src = Wr; dst = WrT; break;
        case 2: src = Wg; dst = WgT; break;
        default: src = Wo; dst = WoT; break;
    }
    for (int e = threadIdx.x; e < 128 * 128; e += blockDim.x) {
        int o = e >> 7, i = e & 127;
        dst[e] = f2bf(src[i * 128 + o]);  // WT[o][i] = W[i][o]
    }
}

// ---------------- K1: projection GEMM, output transposed [h][pos] ----------------
template <int COLMODE>
__global__ __launch_bounds__(256) void k_proj(const float* __restrict__ pair,
                                              const s16* __restrict__ WT,
                                              const float* __restrict__ bias,
                                              s16* __restrict__ outT) {
    __shared__ __align__(16) s16 As[128 * 128];  // 32KB, XOR-swizzled rows (256B)
    const int t = threadIdx.x;
    const int b = blockIdx.x;
    const int c0 = b & 511, rb = b >> 9;
    {
        const int p = t >> 1;
        const int dh = (t & 1) << 6;
        long gpos = COLMODE ? ((long)(rb * 128 + p) * 512 + c0) : ((long)b * 128 + p);
        const float* src = pair + gpos * 128 + dh;
        const int swz = (p & 7) << 4;
        char* lrow = (char*)As + p * 256;
#pragma unroll
        for (int g = 0; g < 8; ++g) {
            f32x4 v0 = *(const f32x4*)(src + g * 8);
            f32x4 v1 = *(const f32x4*)(src + g * 8 + 4);
            s16x8 pk;
            pk[0] = f2bf(v0[0]); pk[1] = f2bf(v0[1]); pk[2] = f2bf(v0[2]); pk[3] = f2bf(v0[3]);
            pk[4] = f2bf(v1[0]); pk[5] = f2bf(v1[1]); pk[6] = f2bf(v1[2]); pk[7] = f2bf(v1[3]);
            *(s16x8*)(lrow + ((dh * 2 + g * 16) ^ swz)) = pk;
        }
    }
    __syncthreads();
    const int w = t >> 6, l = t & 63;
    const int wr = (w >> 1) * 64, wc = (w & 1) * 64;
    const int lr = l & 15, lg = l >> 4;
    f32x4 acc[4][4];
#pragma unroll
    for (int mi = 0; mi < 4; ++mi)
#pragma unroll
        for (int ni = 0; ni < 4; ++ni) acc[mi][ni] = (f32x4){0.f, 0.f, 0.f, 0.f};
#pragma unroll
    for (int ks = 0; ks < 4; ++ks) {
        const int kk = ks * 32 + lg * 8;
        s16x8 af[4], bfv[4];
#pragma unroll
        for (int mi = 0; mi < 4; ++mi) {
            int row = wr + mi * 16 + lr;
            af[mi] = *(const s16x8*)((const char*)As + ((row * 256 + kk * 2) ^ ((row & 7) << 4)));
        }
#pragma unroll
        for (int ni = 0; ni < 4; ++ni) {
            int h = wc + ni * 16 + lr;
            bfv[ni] = *(const s16x8*)(WT + h * 128 + kk);
        }
#pragma unroll
        for (int mi = 0; mi < 4; ++mi)
#pragma unroll
            for (int ni = 0; ni < 4; ++ni)
                acc[mi][ni] = __builtin_amdgcn_mfma_f32_16x16x32_bf16(af[mi], bfv[ni], acc[mi][ni], 0, 0, 0);
    }
#pragma unroll
    for (int ni = 0; ni < 4; ++ni) {
        const int h = wc + ni * 16 + lr;
        const float bv = bias[h];
        long base = (long)h * NPOS + (COLMODE ? ((long)c0 * 512 + rb * 128) : ((long)b * 128));
#pragma unroll
        for (int mi = 0; mi < 4; ++mi) {
            const int prow = wr + mi * 16 + lg * 4;
            s16x4 pk;
#pragma unroll
            for (int r = 0; r < 4; ++r) pk[r] = f2bf(acc[mi][ni][r] + bv);
            *(s16x4*)(outT + base + prow) = pk;
        }
    }
}

// ---------------- K2: triangle einsum = 128 batched 512^3 GEMMs ----------------
__global__ __launch_bounds__(256) void k_tri(const s16* __restrict__ leftT,
                                             const s16* __restrict__ rightTT,
                                             s16* __restrict__ tri) {
    __shared__ __align__(16) s16 As[128 * 64];
    __shared__ __align__(16) s16 Bs[128 * 64];
    const int t = threadIdx.x;
    const int logical = ((blockIdx.x & 7) << 8) | (blockIdx.x >> 3);
    const int h = logical >> 4;
    const int ti = (logical >> 2) & 3, tj = logical & 3;
    const s16* Ap = leftT + (long)h * NPOS + ti * 128 * 512;
    const s16* Bp = rightTT + (long)h * NPOS + tj * 128 * 512;
    const int w = t >> 6, l = t & 63;
    const int wr = (w >> 1) * 64, wc = (w & 1) * 64;
    const int lr = l & 15, lg = l >> 4;
    const int srow = t >> 3;
    const int skk = (t & 7) << 3;
    f32x4 acc[4][4];
#pragma unroll
    for (int mi = 0; mi < 4; ++mi)
#pragma unroll
        for (int ni = 0; ni < 4; ++ni) acc[mi][ni] = (f32x4){0.f, 0.f, 0.f, 0.f};
    for (int kb = 0; kb < 512; kb += 64) {
        __syncthreads();
#pragma unroll
        for (int P = 0; P < 4; ++P) {
            int row = P * 32 + srow;
            int kks = skk ^ ((row & 7) << 3);
            unsigned loff = P * 4096 + w * 1024;
            gload_lds16(Ap + row * 512 + kb + kks, (char*)As + loff);
            gload_lds16(Bp + row * 512 + kb + kks, (char*)Bs + loff);
        }
        __syncthreads();
#pragma unroll
        for (int ks = 0; ks < 2; ++ks) {
            const int kk = ks * 32 + lg * 8;
            s16x8 af[4], bfv[4];
#pragma unroll
            for (int mi = 0; mi < 4; ++mi) {
                int row = wr + mi * 16 + lr;
                af[mi] = *(const s16x8*)((const char*)As + ((row * 128 + kk * 2) ^ ((row & 7) << 4)));
            }
#pragma unroll
            for (int ni = 0; ni < 4; ++ni) {
                int row = wc + ni * 16 + lr;
                bfv[ni] = *(const s16x8*)((const char*)Bs + ((row * 128 + kk * 2) ^ ((row & 7) << 4)));
            }
#pragma unroll
            for (int mi = 0; mi < 4; ++mi)
#pragma unroll
                for (int ni = 0; ni < 4; ++ni)
                    acc[mi][ni] = __builtin_amdgcn_mfma_f32_16x16x32_bf16(af[mi], bfv[ni], acc[mi][ni], 0, 0, 0);
        }
    }
#pragma unroll
    for (int mi = 0; mi < 4; ++mi) {
#pragma unroll
        for (int r = 0; r < 4; ++r) {
            int i = ti * 128 + wr + mi * 16 + lg * 4 + r;
            s16* dst = tri + (long)h * NPOS + (long)i * 512 + tj * 128 + wc;
#pragma unroll
            for (int ni = 0; ni < 4; ++ni) dst[ni * 16 + lr] = f2bf(acc[mi][ni][r]);
        }
    }
}

// ---------------- K2b: transpose tri[h][pos] -> triT[pos][h] ----------------
// Tile: 128 h x 256 pos (64KB LDS). Stage: gload_lds16 linear dest, source
// pre-swizzled on 16B units by g(h)=(h>>3)&7 (involution). Read-out: thread
// packs 8 h-values (scalar LDS reads, ~2-way conflicts) -> 16B coalesced store
// (waves write 4 x 256B-contiguous rows per iteration).
__global__ __launch_bounds__(256) void k_trT(const s16* __restrict__ tri,
                                             s16* __restrict__ triT) {
    __shared__ __align__(16) s16 Ts[128 * 256];  // 64KB, [h][pos] swizzled
    const int t = threadIdx.x;
    const int w = t >> 6;
    const long posBase = (long)blockIdx.x * 256;
#pragma unroll
    for (int P = 0; P < 16; ++P) {
        const int S = P * 256 + t;          // 16B unit slot
        const int h = S >> 5, u = S & 31;   // 32 units (512B) per h-row
        const int ug = u ^ ((h >> 3) & 7);  // pre-swizzle source
        gload_lds16(tri + (long)h * NPOS + posBase + (ug << 3),
                    (char*)Ts + (P * 256 + w * 64) * 16);
    }
    __syncthreads();
    const int hc = t & 15;   // h-chunk: h = hc*8 .. +8
    const int pr = t >> 4;   // pos offset stride-16
    const int g = hc & 7;    // read-side swizzle for these h
#pragma unroll
    for (int it = 0; it < 16; ++it) {
        const int p = pr + it * 16;
        const int pu = (p >> 3) ^ g, po = p & 7;
        s16x8 pk;
#pragma unroll
        for (int j = 0; j < 8; ++j)
            pk[j] = Ts[(hc * 8 + j) * 256 + pu * 8 + po];
        *(s16x8*)(triT + (posBase + p) * 128 + hc * 8) = pk;
    }
}

// ---------------- K3: streaming final — no LDS, no barriers ----------------
// out2 = triT@WoT + bo ; gate = sigmoid(pair@WgT + bg) ;
// y = LN(pair + gate*out2)*gamma + beta. Phase-split so each 32KB weight is
// L1-resident during its MFMA phase. All A-operands are coalesced vector loads.
__global__ __launch_bounds__(256) void k_final(const float* __restrict__ pair,
                                               const s16* __restrict__ triT,
                                               const s16* __restrict__ WgT,
                                               const s16* __restrict__ WoT,
                                               const float* __restrict__ bgv,
                                               const float* __restrict__ bov,
                                               const float* __restrict__ gam,
                                               const float* __restrict__ bet,
                                               float* __restrict__ out) {
    const int t = threadIdx.x;
    const int w = t >> 6, l = t & 63;
    const int lr = l & 15, lg = l >> 4;
    const int pw = w << 4;
    const long posT = (long)blockIdx.x * 64;
    const long arow = posT + pw + lr;

    // issue all A-operand loads up front (12 vector loads in flight)
    s16x8 ao[4];
    f32x4 pf0[4], pf1[4];
    {
        const s16* trow = triT + arow * 128;
        const float* prow = pair + arow * 128;
#pragma unroll
        for (int ks = 0; ks < 4; ++ks) {
            const int kk = ks * 32 + lg * 8;
            ao[ks] = *(const s16x8*)(trow + kk);
            pf0[ks] = *(const f32x4*)(prow + kk);
            pf1[ks] = *(const f32x4*)(prow + kk + 4);
        }
    }
    // ---- phase O: accO = triT_tile @ WoT ----
    f32x4 accO[8];
#pragma unroll
    for (int ni = 0; ni < 8; ++ni) accO[ni] = (f32x4){0.f, 0.f, 0.f, 0.f};
#pragma unroll
    for (int ks = 0; ks < 4; ++ks) {
        const int kk = ks * 32 + lg * 8;
#pragma unroll
        for (int ni = 0; ni < 8; ++ni) {
            const int d = ni * 16 + lr;
            s16x8 b8 = *(const s16x8*)(WoT + d * 128 + kk);
            accO[ni] = __builtin_amdgcn_mfma_f32_16x16x32_bf16(ao[ks], b8, accO[ni], 0, 0, 0);
        }
    }
    // ---- phase G: accG = pair_tile @ WgT ----
    f32x4 accG[8];
#pragma unroll
    for (int ni = 0; ni < 8; ++ni) accG[ni] = (f32x4){0.f, 0.f, 0.f, 0.f};
#pragma unroll
    for (int ks = 0; ks < 4; ++ks) {
        s16x8 ag;
        ag[0] = f2bf(pf0[ks][0]); ag[1] = f2bf(pf0[ks][1]);
        ag[2] = f2bf(pf0[ks][2]); ag[3] = f2bf(pf0[ks][3]);
        ag[4] = f2bf(pf1[ks][0]); ag[5] = f2bf(pf1[ks][1]);
        ag[6] = f2bf(pf1[ks][2]); ag[7] = f2bf(pf1[ks][3]);
        const int kk = ks * 32 + lg * 8;
#pragma unroll
        for (int ni = 0; ni < 8; ++ni) {
            const int d = ni * 16 + lr;
            s16x8 b8 = *(const s16x8*)(WgT + d * 128 + kk);
            accG[ni] = __builtin_amdgcn_mfma_f32_16x16x32_bf16(ag, b8, accG[ni], 0, 0, 0);
        }
    }
    // ---- P3: gate, residual (pair re-read hits L1/L2 — same lines as pf) ----
    float xv[8][4];
#pragma unroll
    for (int ni = 0; ni < 8; ++ni) {
        const int d = ni * 16 + lr;
        const float bgs = bgv[d], bos = bov[d];
#pragma unroll
        for (int r = 0; r < 4; ++r) {
            const long pos = posT + pw + lg * 4 + r;
            const float pv = pair[pos * 128 + d];
            const float gl = accG[ni][r] + bgs;
            const float gate = 1.f / (1.f + __expf(-gl));
            xv[ni][r] = pv + gate * (accO[ni][r] + bos);
        }
    }
    // ---- P4: LayerNorm over d (16 lr-lanes x 8 frags) + stores ----
    float gmv[8], btv[8];
#pragma unroll
    for (int ni = 0; ni < 8; ++ni) {
        const int d = ni * 16 + lr;
        gmv[ni] = gam[d];
        btv[ni] = bet[d];
    }
#pragma unroll
    for (int r = 0; r < 4; ++r) {
        float s = 0.f;
#pragma unroll
        for (int ni = 0; ni < 8; ++ni) s += xv[ni][r];
        s += __shfl_xor(s, 1); s += __shfl_xor(s, 2);
        s += __shfl_xor(s, 4); s += __shfl_xor(s, 8);
        const float mu = s * 0.0078125f;
        float v = 0.f;
#pragma unroll
        for (int ni = 0; ni < 8; ++ni) { float dd = xv[ni][r] - mu; v += dd * dd; }
        v += __shfl_xor(v, 1); v += __shfl_xor(v, 2);
        v += __shfl_xor(v, 4); v += __shfl_xor(v, 8);
        const float rstd = rsqrtf(v * 0.0078125f + 1e-5f);
        const long pos = posT + pw + lg * 4 + r;
#pragma unroll
        for (int ni = 0; ni < 8; ++ni) {
            const int d = ni * 16 + lr;
            out[pos * 128 + d] = (xv[ni][r] - mu) * rstd * gmv[ni] + btv[ni];
        }
    }
}

extern "C" void kernel_launch(void* const* d_in, const int* in_sizes, int n_in,
                              void* d_out, int out_size, void* d_ws, size_t ws_size,
                              hipStream_t stream) {
    const float* pair = (const float*)d_in[0];
    const float* Wl   = (const float*)d_in[1];
    const float* bl   = (const float*)d_in[2];
    const float* Wr   = (const float*)d_in[3];
    const float* br   = (const float*)d_in[4];
    const float* Wo   = (const float*)d_in[5];
    const float* bo   = (const float*)d_in[6];
    const float* Wg   = (const float*)d_in[7];
    const float* bg   = (const float*)d_in[8];
    const float* gam  = (const float*)d_in[9];
    const float* bet  = (const float*)d_in[10];
    float* out = (float*)d_out;

    s16* WlT = (s16*)d_ws;
    s16* WrT = WlT + 128 * 128;
    s16* WgT = WrT + 128 * 128;
    s16* WoT = WgT + 128 * 128;
    s16* leftT   = WoT + 128 * 128;            // [128][NPOS]; becomes triT after k_tri
    s16* rightTT = leftT + (long)128 * NPOS;   // [128][NPOS]
    s16* tri     = rightTT + (long)128 * NPOS; // [128][NPOS]
    s16* triT    = leftT;                      // [NPOS][128] (leftT is dead after k_tri)

    k_prep<<<4, 256, 0, stream>>>(Wl, Wr, Wg, Wo, WlT, WrT, WgT, WoT);
    k_proj<0><<<2048, 256, 0, stream>>>(pair, WlT, bl, leftT);
    k_proj<1><<<2048, 256, 0, stream>>>(pair, WrT, br, rightTT);
    k_tri<<<2048, 256, 0, stream>>>(leftT, rightTT, tri);
    k_trT<<<1024, 256, 0, stream>>>(tri, triT);
    k_final<<<4096, 256, 0, stream>>>(pair, triT, WgT, WoT, bg, bo, gam, bet, out);
}